// Round 2
// baseline (268.952 us; speedup 1.0000x reference)
//
#include <hip/hip_runtime.h>
#include <math.h>

#define N_RES 1024
#define N_ATOMS 37
#define ATOM_CA 1
#define NBATCH 256
#define SLICES 4              // blocks per batch in pass 1
#define NSUM 34
// sums layout per partial row:
// 0: M = sum m
// 1-3: Sp = sum m*p          4-6: St = sum m*t
// 7: Qp = sum m*|p|^2        8: Qt = sum m*|t|^2
// 9-17: Cpt[i][j] = sum m*p_i*t_j
// 18: S2 = sum m^2
// 19-21: S2p = sum m^2*p     22-24: S2t = sum m^2*t
// 25-33: C2[i][j] = sum m^2*p_i*t_j

// Pass 1: 1024 blocks (4 per batch) x 256 threads, one residue per thread.
// Writes float partials[1024][NSUM] into d_ws.
__global__ __launch_bounds__(256) void rmsd_moments_kernel(
    const float* __restrict__ pred, const float* __restrict__ truec,
    const float* __restrict__ mask, float* __restrict__ partials)
{
    const int blk   = blockIdx.x;          // 0..1023
    const int b     = blk >> 2;            // batch
    const int slice = blk & 3;
    const int tid   = threadIdx.x;
    const int n     = slice * 256 + tid;   // residue index

    const size_t resStride = (size_t)N_ATOMS * 3;
    const float* pp = pred  + ((size_t)b * N_RES + n) * resStride + ATOM_CA * 3;
    const float* tt = truec + ((size_t)b * N_RES + n) * resStride + ATOM_CA * 3;
    const float  m  = mask[((size_t)b * N_RES + n) * N_ATOMS + ATOM_CA];

    const float p0 = pp[0], p1 = pp[1], p2 = pp[2];
    const float t0 = tt[0], t1 = tt[1], t2 = tt[2];
    const float m2 = m * m;

    float acc[NSUM];
    acc[0] = m;
    acc[1] = m * p0;  acc[2] = m * p1;  acc[3] = m * p2;
    acc[4] = m * t0;  acc[5] = m * t1;  acc[6] = m * t2;
    acc[7] = m * (p0*p0 + p1*p1 + p2*p2);
    acc[8] = m * (t0*t0 + t1*t1 + t2*t2);
    acc[9]  = m * p0 * t0; acc[10] = m * p0 * t1; acc[11] = m * p0 * t2;
    acc[12] = m * p1 * t0; acc[13] = m * p1 * t1; acc[14] = m * p1 * t2;
    acc[15] = m * p2 * t0; acc[16] = m * p2 * t1; acc[17] = m * p2 * t2;
    acc[18] = m2;
    acc[19] = m2 * p0; acc[20] = m2 * p1; acc[21] = m2 * p2;
    acc[22] = m2 * t0; acc[23] = m2 * t1; acc[24] = m2 * t2;
    acc[25] = m2 * p0 * t0; acc[26] = m2 * p0 * t1; acc[27] = m2 * p0 * t2;
    acc[28] = m2 * p1 * t0; acc[29] = m2 * p1 * t1; acc[30] = m2 * p1 * t2;
    acc[31] = m2 * p2 * t0; acc[32] = m2 * p2 * t1; acc[33] = m2 * p2 * t2;

    // wave(64) shuffle reduce
#pragma unroll
    for (int i = 0; i < NSUM; ++i) {
        float v = acc[i];
#pragma unroll
        for (int off = 32; off > 0; off >>= 1) v += __shfl_down(v, off, 64);
        acc[i] = v;
    }

    __shared__ float partial[4][NSUM];
    const int wave = tid >> 6, lane = tid & 63;
    if (lane == 0) {
#pragma unroll
        for (int i = 0; i < NSUM; ++i) partial[wave][i] = acc[i];
    }
    __syncthreads();
    if (tid < NSUM) {
        partials[(size_t)blk * NSUM + tid] =
            partial[0][tid] + partial[1][tid] + partial[2][tid] + partial[3][tid];
    }
}

// Pass 2: one block, 256 threads; thread b = batch b. Combine 4 partials in
// fp64, solve the 3x3 Kabsch problem (fp32 Jacobi on Horn's 4x4 N matrix;
// rotation error enters D only at 2nd order), assemble D in fp64, then
// block-reduce the mean of the 256 RMSDs.
__global__ __launch_bounds__(256) void rmsd_finish_kernel(
    const float* __restrict__ partials, float* __restrict__ out)
{
    const int b = threadIdx.x;

    double s[NSUM];
#pragma unroll
    for (int i = 0; i < NSUM; ++i) s[i] = 0.0;
#pragma unroll
    for (int k = 0; k < SLICES; ++k) {
        const float* row = partials + ((size_t)b * SLICES + k) * NSUM;
#pragma unroll
        for (int i = 0; i < NSUM; ++i) s[i] += (double)row[i];
    }

    const double M   = s[0];
    const double Mep = M + 1e-8;
    double Sp[3] = { s[1], s[2], s[3] };
    double St[3] = { s[4], s[5], s[6] };
    double pc[3] = { Sp[0] / Mep, Sp[1] / Mep, Sp[2] / Mep };
    double tc[3] = { St[0] / Mep, St[1] / Mep, St[2] / Mep };
    const double Qp = s[7], Qt = s[8];
    const double S2 = s[18];
    double S2p[3] = { s[19], s[20], s[21] };
    double S2t[3] = { s[22], s[23], s[24] };

    // H[i][j] = sum m^2 (p-pc)_i (t-tc)_j
    double H[3][3];
#pragma unroll
    for (int i = 0; i < 3; ++i)
#pragma unroll
        for (int j = 0; j < 3; ++j)
            H[i][j] = s[25 + i * 3 + j] - pc[i] * S2t[j] - tc[j] * S2p[i]
                    + pc[i] * tc[j] * S2;

    // Horn 4x4 N matrix (fp32 from here; D is stationary in R at the optimum)
    const float Sxx = (float)H[0][0], Sxy = (float)H[0][1], Sxz = (float)H[0][2];
    const float Syx = (float)H[1][0], Syy = (float)H[1][1], Syz = (float)H[1][2];
    const float Szx = (float)H[2][0], Szy = (float)H[2][1], Szz = (float)H[2][2];
    float A[4][4] = {
        { Sxx + Syy + Szz, Syz - Szy,        Szx - Sxz,        Sxy - Syx },
        { Syz - Szy,       Sxx - Syy - Szz,  Sxy + Syx,        Szx + Sxz },
        { Szx - Sxz,       Sxy + Syx,       -Sxx + Syy - Szz,  Syz + Szy },
        { Sxy - Syx,       Szx + Sxz,        Syz + Szy,       -Sxx - Syy + Szz }
    };
    float Vm[4][4] = { {1,0,0,0},{0,1,0,0},{0,0,1,0},{0,0,0,1} };

#pragma unroll
    for (int sweep = 0; sweep < 8; ++sweep) {
#pragma unroll
        for (int p = 0; p < 3; ++p) {
#pragma unroll
            for (int q = p + 1; q < 4; ++q) {
                const float apq = A[p][q];
                const float denom = fabsf(apq) > 1e-20f ? apq : 1e-20f;
                const float theta = (A[q][q] - A[p][p]) / (2.0f * denom);
                float tt = (theta >= 0.0f ? 1.0f : -1.0f)
                         / (fabsf(theta) + sqrtf(theta * theta + 1.0f));
                if (fabsf(apq) <= 1e-20f) tt = 0.0f;   // no-op rotation
                const float c = 1.0f / sqrtf(tt * tt + 1.0f);
                const float sn = tt * c;
#pragma unroll
                for (int k = 0; k < 4; ++k) {
                    const float akp = A[k][p], akq = A[k][q];
                    A[k][p] = c * akp - sn * akq;
                    A[k][q] = sn * akp + c * akq;
                }
#pragma unroll
                for (int k = 0; k < 4; ++k) {
                    const float apk = A[p][k], aqk = A[q][k];
                    A[p][k] = c * apk - sn * aqk;
                    A[q][k] = sn * apk + c * aqk;
                }
#pragma unroll
                for (int k = 0; k < 4; ++k) {
                    const float vkp = Vm[k][p], vkq = Vm[k][q];
                    Vm[k][p] = c * vkp - sn * vkq;
                    Vm[k][q] = sn * vkp + c * vkq;
                }
            }
        }
    }
    int best = 0;
#pragma unroll
    for (int i = 1; i < 4; ++i) if (A[i][i] > A[best][best]) best = i;
    float q0 = Vm[0][best], qx = Vm[1][best], qy = Vm[2][best], qz = Vm[3][best];
    const float nq = sqrtf(q0*q0 + qx*qx + qy*qy + qz*qz);
    q0 /= nq; qx /= nq; qy /= nq; qz /= nq;

    double R[3][3] = {
        { 1.0 - 2.0*((double)qy*qy + (double)qz*qz), 2.0*((double)qx*qy - (double)qz*q0), 2.0*((double)qx*qz + (double)qy*q0) },
        { 2.0*((double)qx*qy + (double)qz*q0), 1.0 - 2.0*((double)qx*qx + (double)qz*qz), 2.0*((double)qy*qz - (double)qx*q0) },
        { 2.0*((double)qx*qz - (double)qy*q0), 2.0*((double)qy*qz + (double)qx*q0), 1.0 - 2.0*((double)qx*qx + (double)qy*qy) }
    };

    // G[i][j] = sum m (t-tc)_i (p-pc)_j ; cross = sum_ij R[i][j]*G[i][j]
    double cross = 0.0;
#pragma unroll
    for (int i = 0; i < 3; ++i)
#pragma unroll
        for (int j = 0; j < 3; ++j) {
            const double Gij = s[9 + j * 3 + i] - tc[i] * Sp[j] - pc[j] * St[i]
                             + tc[i] * pc[j] * M;
            cross += R[i][j] * Gij;
        }

    const double Qpc = Qp - 2.0*(pc[0]*Sp[0] + pc[1]*Sp[1] + pc[2]*Sp[2])
                     + (pc[0]*pc[0] + pc[1]*pc[1] + pc[2]*pc[2]) * M;
    const double Qtc = Qt - 2.0*(tc[0]*St[0] + tc[1]*St[1] + tc[2]*St[2])
                     + (tc[0]*tc[0] + tc[1]*tc[1] + tc[2]*tc[2]) * M;
    double D = Qpc + Qtc - 2.0 * cross;
    if (D < 0.0) D = 0.0;
    float rmsd = (float)sqrt(D / Mep);

    // mean over 256 batches
#pragma unroll
    for (int off = 32; off > 0; off >>= 1) rmsd += __shfl_down(rmsd, off, 64);
    __shared__ float part[4];
    if ((threadIdx.x & 63) == 0) part[threadIdx.x >> 6] = rmsd;
    __syncthreads();
    if (threadIdx.x == 0)
        out[0] = (part[0] + part[1] + part[2] + part[3]) * (1.0f / (float)NBATCH);
}

extern "C" void kernel_launch(void* const* d_in, const int* in_sizes, int n_in,
                              void* d_out, int out_size, void* d_ws, size_t ws_size,
                              hipStream_t stream) {
    const float* pred  = (const float*)d_in[0];
    const float* truec = (const float*)d_in[1];
    const float* mask  = (const float*)d_in[2];
    float* out = (float*)d_out;
    float* partials = (float*)d_ws;   // 1024 * 34 floats = 139264 B

    rmsd_moments_kernel<<<NBATCH * SLICES, 256, 0, stream>>>(pred, truec, mask, partials);
    rmsd_finish_kernel<<<1, 256, 0, stream>>>(partials, out);
}

// Round 3
// 239.207 us; speedup vs baseline: 1.1244x; 1.1244x over previous
//
#include <hip/hip_runtime.h>
#include <math.h>

#define N_RES 1024
#define N_ATOMS 37
#define ATOM_CA 1
#define NBATCH 256
#define SLICES 4              // blocks per batch in pass 1
#define NSUM 36
// sums layout per partial row:
// 0: M = sum m
// 1-3: Sp = sum m*p          4-6: St = sum m*t
// 7: Qp = sum m*|p|^2        8: Qt = sum m*|t|^2
// 9-17: Cpt[i][j] = sum m*p_i*t_j
// 18: S2 = sum m^2
// 19-21: S2p = sum m^2*p     22-24: S2t = sum m^2*t
// 25-33: C2[i][j] = sum m^2*p_i*t_j
// 34: Qp2 = sum m^2*|p|^2    35: Qt2 = sum m^2*|t|^2

// Pass 1: 1024 blocks (4 per batch) x 256 threads, one residue per thread.
// Writes float partials[1024][NSUM] into d_ws.
__global__ __launch_bounds__(256) void rmsd_moments_kernel(
    const float* __restrict__ pred, const float* __restrict__ truec,
    const float* __restrict__ mask, float* __restrict__ partials)
{
    const int blk   = blockIdx.x;          // 0..1023
    const int b     = blk >> 2;            // batch
    const int slice = blk & 3;
    const int tid   = threadIdx.x;
    const int n     = slice * 256 + tid;   // residue index

    const size_t resStride = (size_t)N_ATOMS * 3;
    const float* pp = pred  + ((size_t)b * N_RES + n) * resStride + ATOM_CA * 3;
    const float* tt = truec + ((size_t)b * N_RES + n) * resStride + ATOM_CA * 3;
    const float  m  = mask[((size_t)b * N_RES + n) * N_ATOMS + ATOM_CA];

    const float p0 = pp[0], p1 = pp[1], p2 = pp[2];
    const float t0 = tt[0], t1 = tt[1], t2 = tt[2];
    const float m2 = m * m;
    const float np = p0*p0 + p1*p1 + p2*p2;
    const float nt = t0*t0 + t1*t1 + t2*t2;

    float acc[NSUM];
    acc[0] = m;
    acc[1] = m * p0;  acc[2] = m * p1;  acc[3] = m * p2;
    acc[4] = m * t0;  acc[5] = m * t1;  acc[6] = m * t2;
    acc[7] = m * np;
    acc[8] = m * nt;
    acc[9]  = m * p0 * t0; acc[10] = m * p0 * t1; acc[11] = m * p0 * t2;
    acc[12] = m * p1 * t0; acc[13] = m * p1 * t1; acc[14] = m * p1 * t2;
    acc[15] = m * p2 * t0; acc[16] = m * p2 * t1; acc[17] = m * p2 * t2;
    acc[18] = m2;
    acc[19] = m2 * p0; acc[20] = m2 * p1; acc[21] = m2 * p2;
    acc[22] = m2 * t0; acc[23] = m2 * t1; acc[24] = m2 * t2;
    acc[25] = m2 * p0 * t0; acc[26] = m2 * p0 * t1; acc[27] = m2 * p0 * t2;
    acc[28] = m2 * p1 * t0; acc[29] = m2 * p1 * t1; acc[30] = m2 * p1 * t2;
    acc[31] = m2 * p2 * t0; acc[32] = m2 * p2 * t1; acc[33] = m2 * p2 * t2;
    acc[34] = m2 * np;
    acc[35] = m2 * nt;

    // wave(64) shuffle reduce
#pragma unroll
    for (int i = 0; i < NSUM; ++i) {
        float v = acc[i];
#pragma unroll
        for (int off = 32; off > 0; off >>= 1) v += __shfl_down(v, off, 64);
        acc[i] = v;
    }

    __shared__ float partial[4][NSUM];
    const int wave = tid >> 6, lane = tid & 63;
    if (lane == 0) {
#pragma unroll
        for (int i = 0; i < NSUM; ++i) partial[wave][i] = acc[i];
    }
    __syncthreads();
    if (tid < NSUM) {
        partials[(size_t)blk * NSUM + tid] =
            partial[0][tid] + partial[1][tid] + partial[2][tid] + partial[3][tid];
    }
}

// Pass 2: one block, 256 threads; thread b = batch b. Combine 4 partials in
// fp64, then Theobald QCP: lambda_max of Horn's 4x4 K matrix via Newton on
// the characteristic quartic. cross-term = lambda_max (binary mask =>
// m == m^2 weighting). Pure register-resident scalar math — no arrays with
// dynamic indices (round-2 lesson: PromoteAlloca sent Jacobi's matrices to
// LDS, 144 us).
__global__ __launch_bounds__(256) void rmsd_finish_kernel(
    const float* __restrict__ partials, float* __restrict__ out)
{
    const int b = threadIdx.x;

    double s[NSUM];
#pragma unroll
    for (int i = 0; i < NSUM; ++i) s[i] = 0.0;
#pragma unroll
    for (int k = 0; k < SLICES; ++k) {
        const float* row = partials + ((size_t)b * SLICES + k) * NSUM;
#pragma unroll
        for (int i = 0; i < NSUM; ++i) s[i] += (double)row[i];
    }

    const double M   = s[0];
    const double Mep = M + 1e-8;
    const double Sp0 = s[1], Sp1 = s[2], Sp2 = s[3];
    const double St0 = s[4], St1 = s[5], St2 = s[6];
    const double pc0 = Sp0 / Mep, pc1 = Sp1 / Mep, pc2 = Sp2 / Mep;
    const double tc0 = St0 / Mep, tc1 = St1 / Mep, tc2 = St2 / Mep;
    const double Qp = s[7], Qt = s[8];
    const double S2 = s[18];
    const double S2p0 = s[19], S2p1 = s[20], S2p2 = s[21];
    const double S2t0 = s[22], S2t1 = s[23], S2t2 = s[24];
    const double Qp2 = s[34], Qt2 = s[35];

    // H[i][j] = sum m^2 (p-pc)_i (t-tc)_j   (m^2-weighted, reference semantics)
    const double Sxx = s[25] - pc0 * S2t0 - tc0 * S2p0 + pc0 * tc0 * S2;
    const double Sxy = s[26] - pc0 * S2t1 - tc1 * S2p0 + pc0 * tc1 * S2;
    const double Sxz = s[27] - pc0 * S2t2 - tc2 * S2p0 + pc0 * tc2 * S2;
    const double Syx = s[28] - pc1 * S2t0 - tc0 * S2p1 + pc1 * tc0 * S2;
    const double Syy = s[29] - pc1 * S2t1 - tc1 * S2p1 + pc1 * tc1 * S2;
    const double Syz = s[30] - pc1 * S2t2 - tc2 * S2p1 + pc1 * tc2 * S2;
    const double Szx = s[31] - pc2 * S2t0 - tc0 * S2p2 + pc2 * tc0 * S2;
    const double Szy = s[32] - pc2 * S2t1 - tc1 * S2p2 + pc2 * tc1 * S2;
    const double Szz = s[33] - pc2 * S2t2 - tc2 * S2p2 + pc2 * tc2 * S2;

    // GA2 = sum m^2 |p-pc|^2 ; GB2 = sum m^2 |t-tc|^2  (Newton start bound)
    const double GA2 = Qp2 - 2.0*(pc0*S2p0 + pc1*S2p1 + pc2*S2p2)
                     + (pc0*pc0 + pc1*pc1 + pc2*pc2) * S2;
    const double GB2 = Qt2 - 2.0*(tc0*S2t0 + tc1*S2t1 + tc2*S2t2)
                     + (tc0*tc0 + tc1*tc1 + tc2*tc2) * S2;

    // ---- QCP characteristic quartic: x^4 + C2 x^2 + C1 x + C0 ----
    const double Sxx2 = Sxx*Sxx, Syy2 = Syy*Syy, Szz2 = Szz*Szz;
    const double Sxy2 = Sxy*Sxy, Syz2 = Syz*Syz, Sxz2 = Sxz*Sxz;
    const double Syx2 = Syx*Syx, Szy2 = Szy*Szy, Szx2 = Szx*Szx;

    const double SyzSzymSyySzz2 = 2.0*(Syz*Szy - Syy*Szz);
    const double Sxx2Syy2Szz2Syz2Szy2 = Syy2 + Szz2 - Sxx2 + Syz2 + Szy2;

    const double C2 = -2.0*(Sxx2 + Syy2 + Szz2 + Sxy2 + Syx2 + Sxz2 + Szx2 + Syz2 + Szy2);
    const double C1 = 8.0*(Sxx*Syz*Szy + Syy*Szx*Sxz + Szz*Sxy*Syx
                         - Sxx*Syy*Szz - Syz*Szx*Sxy - Szy*Syx*Sxz);

    const double SxzpSzx = Sxz + Szx;
    const double SyzpSzy = Syz + Szy;
    const double SxypSyx = Sxy + Syx;
    const double SyzmSzy = Syz - Szy;
    const double SxzmSzx = Sxz - Szx;
    const double SxymSyx = Sxy - Syx;
    const double SxxpSyy = Sxx + Syy;
    const double SxxmSyy = Sxx - Syy;
    const double Sxy2Sxz2Syx2Szx2 = Sxy2 + Sxz2 - Syx2 - Szx2;

    const double C0 =
        Sxy2Sxz2Syx2Szx2 * Sxy2Sxz2Syx2Szx2
      + (Sxx2Syy2Szz2Syz2Szy2 + SyzSzymSyySzz2) * (Sxx2Syy2Szz2Syz2Szy2 - SyzSzymSyySzz2)
      + (-(SxzpSzx)*(SyzmSzy) + (SxymSyx)*(SxxmSyy - Szz)) *
        (-(SxzmSzx)*(SyzpSzy) + (SxymSyx)*(SxxmSyy + Szz))
      + (-(SxzpSzx)*(SyzpSzy) - (SxypSyx)*(SxxpSyy - Szz)) *
        (-(SxzmSzx)*(SyzmSzy) - (SxypSyx)*(SxxpSyy + Szz))
      + ( (SxypSyx)*(SyzpSzy) + (SxzpSzx)*(SxxmSyy + Szz)) *
        (-(SxymSyx)*(SyzmSzy) + (SxzpSzx)*(SxxpSyy + Szz))
      + ( (SxypSyx)*(SyzmSzy) + (SxzmSzx)*(SxxmSyy - Szz)) *
        (-(SxymSyx)*(SyzpSzy) + (SxzmSzx)*(SxxpSyy - Szz));

    // Newton from above: lambda0 = (GA2+GB2)/2 >= lambda_max
    double lam = 0.5 * (GA2 + GB2);
#pragma unroll
    for (int it = 0; it < 40; ++it) {
        const double x2 = lam * lam;
        const double bq = (x2 + C2) * lam;
        const double aq = bq + C1;
        const double den = 2.0 * x2 * lam + bq + aq;
        const double num = aq * lam + C0;
        const double d = (fabs(den) > 1e-300) ? (num / den) : 0.0;
        lam -= d;
    }

    // cross term (m-weighted) == lambda_max (m^2) for binary masks.
    // D = sum m|p-pc|^2 + sum m|t-tc|^2 - 2*lambda
    const double Qpc = Qp - 2.0*(pc0*Sp0 + pc1*Sp1 + pc2*Sp2)
                     + (pc0*pc0 + pc1*pc1 + pc2*pc2) * M;
    const double Qtc = Qt - 2.0*(tc0*St0 + tc1*St1 + tc2*St2)
                     + (tc0*tc0 + tc1*tc1 + tc2*tc2) * M;
    double D = Qpc + Qtc - 2.0 * lam;
    if (D < 0.0) D = 0.0;
    float rmsd = (float)sqrt(D / Mep);

    // mean over 256 batches
#pragma unroll
    for (int off = 32; off > 0; off >>= 1) rmsd += __shfl_down(rmsd, off, 64);
    __shared__ float part[4];
    if ((threadIdx.x & 63) == 0) part[threadIdx.x >> 6] = rmsd;
    __syncthreads();
    if (threadIdx.x == 0)
        out[0] = (part[0] + part[1] + part[2] + part[3]) * (1.0f / (float)NBATCH);
}

extern "C" void kernel_launch(void* const* d_in, const int* in_sizes, int n_in,
                              void* d_out, int out_size, void* d_ws, size_t ws_size,
                              hipStream_t stream) {
    const float* pred  = (const float*)d_in[0];
    const float* truec = (const float*)d_in[1];
    const float* mask  = (const float*)d_in[2];
    float* out = (float*)d_out;
    float* partials = (float*)d_ws;   // 1024 * 36 floats = 147456 B

    rmsd_moments_kernel<<<NBATCH * SLICES, 256, 0, stream>>>(pred, truec, mask, partials);
    rmsd_finish_kernel<<<1, 256, 0, stream>>>(partials, out);
}

// Round 4
// 237.383 us; speedup vs baseline: 1.1330x; 1.0077x over previous
//
#include <hip/hip_runtime.h>
#include <math.h>

#define N_RES 1024
#define N_ATOMS 37
#define ATOM_CA 1
#define NBATCH 256
#define SLICES 4              // blocks per batch in pass 1
#define NSUM 18
// Mask is binary ({0,1}) => m^2 == m, so the m^2-weighted moments equal the
// m-weighted ones (round-3 carried both; that doubled the shuffle-reduce DS
// traffic for nothing). sums layout per partial row:
// 0: M = sum m
// 1-3: Sp = sum m*p          4-6: St = sum m*t
// 7: Qp = sum m*|p|^2        8: Qt = sum m*|t|^2
// 9-17: Cpt[i][j] = sum m*p_i*t_j

// Pass 1: 1024 blocks (4 per batch) x 256 threads, one residue per thread.
// Writes float partials[1024][NSUM] into d_ws.
__global__ __launch_bounds__(256) void rmsd_moments_kernel(
    const float* __restrict__ pred, const float* __restrict__ truec,
    const float* __restrict__ mask, float* __restrict__ partials)
{
    const int blk   = blockIdx.x;          // 0..1023
    const int b     = blk >> 2;            // batch
    const int slice = blk & 3;
    const int tid   = threadIdx.x;
    const int n     = slice * 256 + tid;   // residue index

    const size_t resStride = (size_t)N_ATOMS * 3;
    const float* pp = pred  + ((size_t)b * N_RES + n) * resStride + ATOM_CA * 3;
    const float* tt = truec + ((size_t)b * N_RES + n) * resStride + ATOM_CA * 3;
    const float  m  = mask[((size_t)b * N_RES + n) * N_ATOMS + ATOM_CA];

    const float p0 = pp[0], p1 = pp[1], p2 = pp[2];
    const float t0 = tt[0], t1 = tt[1], t2 = tt[2];

    float acc[NSUM];
    acc[0] = m;
    acc[1] = m * p0;  acc[2] = m * p1;  acc[3] = m * p2;
    acc[4] = m * t0;  acc[5] = m * t1;  acc[6] = m * t2;
    acc[7] = m * (p0*p0 + p1*p1 + p2*p2);
    acc[8] = m * (t0*t0 + t1*t1 + t2*t2);
    acc[9]  = m * p0 * t0; acc[10] = m * p0 * t1; acc[11] = m * p0 * t2;
    acc[12] = m * p1 * t0; acc[13] = m * p1 * t1; acc[14] = m * p1 * t2;
    acc[15] = m * p2 * t0; acc[16] = m * p2 * t1; acc[17] = m * p2 * t2;

    // wave(64) shuffle reduce
#pragma unroll
    for (int i = 0; i < NSUM; ++i) {
        float v = acc[i];
#pragma unroll
        for (int off = 32; off > 0; off >>= 1) v += __shfl_down(v, off, 64);
        acc[i] = v;
    }

    __shared__ float partial[4][NSUM];
    const int wave = tid >> 6, lane = tid & 63;
    if (lane == 0) {
#pragma unroll
        for (int i = 0; i < NSUM; ++i) partial[wave][i] = acc[i];
    }
    __syncthreads();
    if (tid < NSUM) {
        partials[(size_t)blk * NSUM + tid] =
            partial[0][tid] + partial[1][tid] + partial[2][tid] + partial[3][tid];
    }
}

// Pass 2: one block, 256 threads; thread b = batch b. Combine 4 partials in
// fp64, then Theobald QCP: lambda_max of Horn's 4x4 K matrix via Newton on
// the characteristic quartic (pure register-resident scalar fp64 — round-2
// lesson: any dynamically-indexed array gets demoted to LDS). Binary mask
// => cross term == lambda_max and m^2 moments == m moments.
__global__ __launch_bounds__(256) void rmsd_finish_kernel(
    const float* __restrict__ partials, float* __restrict__ out)
{
    const int b = threadIdx.x;

    double s[NSUM];
#pragma unroll
    for (int i = 0; i < NSUM; ++i) s[i] = 0.0;
#pragma unroll
    for (int k = 0; k < SLICES; ++k) {
        const float* row = partials + ((size_t)b * SLICES + k) * NSUM;
#pragma unroll
        for (int i = 0; i < NSUM; ++i) s[i] += (double)row[i];
    }

    const double M   = s[0];
    const double Mep = M + 1e-8;
    const double Sp0 = s[1], Sp1 = s[2], Sp2 = s[3];
    const double St0 = s[4], St1 = s[5], St2 = s[6];
    const double pc0 = Sp0 / Mep, pc1 = Sp1 / Mep, pc2 = Sp2 / Mep;
    const double tc0 = St0 / Mep, tc1 = St1 / Mep, tc2 = St2 / Mep;
    const double Qp = s[7], Qt = s[8];

    // H[i][j] = sum m (p-pc)_i (t-tc)_j  (== m^2-weighted for binary mask)
    const double Sxx = s[9]  - pc0 * St0 - tc0 * Sp0 + pc0 * tc0 * M;
    const double Sxy = s[10] - pc0 * St1 - tc1 * Sp0 + pc0 * tc1 * M;
    const double Sxz = s[11] - pc0 * St2 - tc2 * Sp0 + pc0 * tc2 * M;
    const double Syx = s[12] - pc1 * St0 - tc0 * Sp1 + pc1 * tc0 * M;
    const double Syy = s[13] - pc1 * St1 - tc1 * Sp1 + pc1 * tc1 * M;
    const double Syz = s[14] - pc1 * St2 - tc2 * Sp1 + pc1 * tc2 * M;
    const double Szx = s[15] - pc2 * St0 - tc0 * Sp2 + pc2 * tc0 * M;
    const double Szy = s[16] - pc2 * St1 - tc1 * Sp2 + pc2 * tc1 * M;
    const double Szz = s[17] - pc2 * St2 - tc2 * Sp2 + pc2 * tc2 * M;

    // Centered quadratic norms (also the Newton start bound)
    const double Qpc = Qp - 2.0*(pc0*Sp0 + pc1*Sp1 + pc2*Sp2)
                     + (pc0*pc0 + pc1*pc1 + pc2*pc2) * M;
    const double Qtc = Qt - 2.0*(tc0*St0 + tc1*St1 + tc2*St2)
                     + (tc0*tc0 + tc1*tc1 + tc2*tc2) * M;

    // ---- QCP characteristic quartic: x^4 + C2 x^2 + C1 x + C0 ----
    const double Sxx2 = Sxx*Sxx, Syy2 = Syy*Syy, Szz2 = Szz*Szz;
    const double Sxy2 = Sxy*Sxy, Syz2 = Syz*Syz, Sxz2 = Sxz*Sxz;
    const double Syx2 = Syx*Syx, Szy2 = Szy*Szy, Szx2 = Szx*Szx;

    const double SyzSzymSyySzz2 = 2.0*(Syz*Szy - Syy*Szz);
    const double Sxx2Syy2Szz2Syz2Szy2 = Syy2 + Szz2 - Sxx2 + Syz2 + Szy2;

    const double C2 = -2.0*(Sxx2 + Syy2 + Szz2 + Sxy2 + Syx2 + Sxz2 + Szx2 + Syz2 + Szy2);
    const double C1 = 8.0*(Sxx*Syz*Szy + Syy*Szx*Sxz + Szz*Sxy*Syx
                         - Sxx*Syy*Szz - Syz*Szx*Sxy - Szy*Syx*Sxz);

    const double SxzpSzx = Sxz + Szx;
    const double SyzpSzy = Syz + Szy;
    const double SxypSyx = Sxy + Syx;
    const double SyzmSzy = Syz - Szy;
    const double SxzmSzx = Sxz - Szx;
    const double SxymSyx = Sxy - Syx;
    const double SxxpSyy = Sxx + Syy;
    const double SxxmSyy = Sxx - Syy;
    const double Sxy2Sxz2Syx2Szx2 = Sxy2 + Sxz2 - Syx2 - Szx2;

    const double C0 =
        Sxy2Sxz2Syx2Szx2 * Sxy2Sxz2Syx2Szx2
      + (Sxx2Syy2Szz2Syz2Szy2 + SyzSzymSyySzz2) * (Sxx2Syy2Szz2Syz2Szy2 - SyzSzymSyySzz2)
      + (-(SxzpSzx)*(SyzmSzy) + (SxymSyx)*(SxxmSyy - Szz)) *
        (-(SxzmSzx)*(SyzpSzy) + (SxymSyx)*(SxxmSyy + Szz))
      + (-(SxzpSzx)*(SyzpSzy) - (SxypSyx)*(SxxpSyy - Szz)) *
        (-(SxzmSzx)*(SyzmSzy) - (SxypSyx)*(SxxpSyy + Szz))
      + ( (SxypSyx)*(SyzpSzy) + (SxzpSzx)*(SxxmSyy + Szz)) *
        (-(SxymSyx)*(SyzmSzy) + (SxzpSzx)*(SxxpSyy + Szz))
      + ( (SxypSyx)*(SyzmSzy) + (SxzmSzx)*(SxxmSyy - Szz)) *
        (-(SxymSyx)*(SyzpSzy) + (SxzmSzx)*(SxxpSyy - Szz));

    // Newton from above: lambda0 = (Qpc+Qtc)/2 >= lambda_max
    double lam = 0.5 * (Qpc + Qtc);
#pragma unroll
    for (int it = 0; it < 40; ++it) {
        const double x2 = lam * lam;
        const double bq = (x2 + C2) * lam;
        const double aq = bq + C1;
        const double den = 2.0 * x2 * lam + bq + aq;
        const double num = aq * lam + C0;
        const double d = (fabs(den) > 1e-300) ? (num / den) : 0.0;
        lam -= d;
    }

    double D = Qpc + Qtc - 2.0 * lam;
    if (D < 0.0) D = 0.0;
    float rmsd = (float)sqrt(D / Mep);

    // mean over 256 batches
#pragma unroll
    for (int off = 32; off > 0; off >>= 1) rmsd += __shfl_down(rmsd, off, 64);
    __shared__ float part[4];
    if ((threadIdx.x & 63) == 0) part[threadIdx.x >> 6] = rmsd;
    __syncthreads();
    if (threadIdx.x == 0)
        out[0] = (part[0] + part[1] + part[2] + part[3]) * (1.0f / (float)NBATCH);
}

extern "C" void kernel_launch(void* const* d_in, const int* in_sizes, int n_in,
                              void* d_out, int out_size, void* d_ws, size_t ws_size,
                              hipStream_t stream) {
    const float* pred  = (const float*)d_in[0];
    const float* truec = (const float*)d_in[1];
    const float* mask  = (const float*)d_in[2];
    float* out = (float*)d_out;
    float* partials = (float*)d_ws;   // 1024 * 18 floats = 73728 B

    rmsd_moments_kernel<<<NBATCH * SLICES, 256, 0, stream>>>(pred, truec, mask, partials);
    rmsd_finish_kernel<<<1, 256, 0, stream>>>(partials, out);
}